// Round 1
// 69.103 us; speedup vs baseline: 1.0086x; 1.0086x over previous
//
#include <hip/hip_runtime.h>
#include <math.h>

// Problem constants (fixed by setup_inputs)
#define NL 4          // n_latents
#define MM 1024       // codebook entries per latent
#define DD 16         // dim per latent
#define PP 16384      // points = N*H*W
#define PLANE 1024    // H*W
#define NSTRIDE 65536 // z_dim*H*W
#define CHUNK 256     // points per workgroup (quarter plane)
#define NCHUNK (PP / CHUNK)   // 64
#define MGROUP 256    // codes per workgroup (4 waves x 2 strips x 32)
#define NMG (MM / MGROUP)     // 4
#define ZSTR 20       // LDS stride per point in f16 units (16 data + 4 pad = 40B)
#define SCR_STRIDE 33 // f32 words per row in the transpose-reduce scratch (conflict-free)
#define SCR_WAVE 1056 // 32*33 words per wave region

// Schraudolph-style fast 2^x: bitcast(u32(2^23*(x + B))), B = 127 - 0.0353
// (minimax-centered, max rel err ~±3.5%). x <= 0 always here; negative
// 2^23*(x+B) clamps to 0 via v_cvt_u32_f32 => exact flush-to-zero underflow.
#define EXP2_SCALE 8388608.0f            // 2^23
#define EXP2_BIAS  126.9647f             // 127 - sigma*

typedef _Float16 half4v  __attribute__((ext_vector_type(4)));
typedef _Float16 half8v  __attribute__((ext_vector_type(8)));
typedef float    float16v __attribute__((ext_vector_type(16)));

// Per (l, m-group of 256 codes, p-chunk of 256 points); each wave owns 2 strips
// of 32 codes (the B-fragment LDS read is shared by both MFMAs, and NMG 8->4
// halves the z staging redundancy).
//   dd[s] = (m2a2*e_strip_s)(32xK16) . z_tile(K16x32) + biasC[s]  (v_mfma_f32_32x32x16_f16)
//   acc[s][r] += fast_exp2(dd[s][r] + a2*zsq[col])   -- fma/cvt/add, no trans pipe
//
// ROUND 0 RESTRUCTURE (VGPR-pressure theory): the previous version ran
// `#pragma unroll 2` with both strips' dd tiles live simultaneously -> up to
// 64 transient VGPRs on top of acc(32)+biasC(32)+Af(8), busting the 128-VGPR
// cap imposed by __launch_bounds__(256,4) and forcing inner-loop scratch
// spills. This version: unroll 1, software-pipelined LDS prefetch (one
// iteration ahead, clamped index, no branch), and SEQUENTIAL per-strip
// MFMA->consume so only ONE 16-reg dd tile is live at a time. Live set ~108.
//
// Epilogue: per-wave LDS transpose (32x32, stride-33), two sequential passes
// reusing the same wave-private scratch (DS ops per wave are processed in order).
// MFMA 32x32 C/D layout (HW-verified): col=lane&31, row=(reg&3)+8*(reg>>2)+4*(lane>>5)
// A layout (verified rounds 1-6, absmax=0): A[row=lane&31][k=(lane>>5)*8+j]; B same on cols.
__global__ __launch_bounds__(256, 4)
void latent_dist_kernel(const float* __restrict__ z, const float* __restrict__ e,
                        const float* __restrict__ log_sigma, float* __restrict__ S)
{
    const int t    = threadIdx.x;
    const int lane = t & 63;
    const int wave = t >> 6;
    const int ln31 = lane & 31;
    const int hf   = lane >> 5;

    const int bid = blockIdx.x;
    const int c   = bid & (NCHUNK - 1);       // p-chunk (fastest -> mg-sharers 64 apart, same XCD)
    const int mg  = (bid >> 6) & (NMG - 1);   // m-group
    const int l   = bid >> 8;                 // latent

    const float ls    = log_sigma[0];
    const float alpha = -0.5f * __expf(-2.0f * ls);
    const float a2    = alpha * 1.44269504088896340736f; // alpha/ln2
    const float m2a2  = -2.0f * a2;

    // zh (staging, 256*20*2 = 10240B) and scr (transpose-reduce, 4*1056*4 = 16896B)
    // share storage: scr is only used after the main loop's barrier.
    __shared__ __attribute__((aligned(16))) char smem[4 * SCR_WAVE * 4];
    _Float16* zh  = (_Float16*)smem;
    float*    scr = (float*)smem;
    __shared__ float azqs[CHUNK];   // (a2*zsq + EXP2_BIAS) * 2^23  (magic form)
    __shared__ float esqs[MGROUP];

    // ---- Stage z chunk: one point per thread, 16 global f32 (coalesced) -> LDS f16.
    const int n  = c >> 2;                 // 4 chunks per plane
    const int q0 = (c & 3) * CHUNK;
    const float* zb = z + (size_t)n * NSTRIDE + (size_t)l * DD * PLANE + q0;

    float sq = 0.f;
#pragma unroll
    for (int dp = 0; dp < 8; ++dp) {
        float v0 = zb[(2 * dp)     * PLANE + t];
        float v1 = zb[(2 * dp + 1) * PLANE + t];
        sq += v0 * v0 + v1 * v1;
        union { _Float16 h[2]; unsigned u; } pk;
        pk.h[0] = (_Float16)v0; pk.h[1] = (_Float16)v1;
        *(unsigned*)(&zh[t * ZSTR + 2 * dp]) = pk.u; // 4B-aligned packed store
    }
    azqs[t] = (sq * a2 + EXP2_BIAS) * EXP2_SCALE;

    // ---- A fragments for the wave's 2 strips (pre-scaled by m2a2) + exact f32 esq.
    const int m0 = mg * MGROUP + wave * 64;
    half8v Af[2];
#pragma unroll
    for (int s = 0; s < 2; ++s) {
        const float* eb = e + ((size_t)l * MM + m0 + s * 32 + ln31) * DD + hf * 8;
        float4 a0 = *(const float4*)eb;
        float4 a1 = *(const float4*)(eb + 4);
        float esq_p = a0.x*a0.x + a0.y*a0.y + a0.z*a0.z + a0.w*a0.w
                    + a1.x*a1.x + a1.y*a1.y + a1.z*a1.z + a1.w*a1.w;
        esq_p += __shfl_xor(esq_p, 32, 64);       // combine the two k-halves
        esqs[wave * 64 + s * 32 + ln31] = esq_p;  // both halves write same value
        Af[s][0] = (_Float16)(a0.x * m2a2); Af[s][1] = (_Float16)(a0.y * m2a2);
        Af[s][2] = (_Float16)(a0.z * m2a2); Af[s][3] = (_Float16)(a0.w * m2a2);
        Af[s][4] = (_Float16)(a1.x * m2a2); Af[s][5] = (_Float16)(a1.y * m2a2);
        Af[s][6] = (_Float16)(a1.z * m2a2); Af[s][7] = (_Float16)(a1.w * m2a2);
    }

    __syncthreads();

    // C operands = a2*esq[row(r)]: folded into the MFMA, constant over the p-loop.
    float16v biasC[2];
#pragma unroll
    for (int s = 0; s < 2; ++s)
#pragma unroll
        for (int r = 0; r < 16; ++r) {
            const int row = (r & 3) + 8 * (r >> 2) + 4 * hf;
            biasC[s][r] = esqs[wave * 64 + s * 32 + row] * a2;
        }

    float16v acc[2];
#pragma unroll
    for (int s = 0; s < 2; ++s)
#pragma unroll
        for (int r = 0; r < 16; ++r) acc[s][r] = 0.f;

    const _Float16* zrow = zh + ln31 * ZSTR + hf * 8;

    // Software-pipelined prefetch: iteration pt consumes registers loaded at
    // pt-1. Clamped (&7) next-index keeps the loads branch-free; the final
    // (wasted) prefetch re-reads iteration 0's rows (valid addresses).
    float  az = azqs[ln31];
    half4v b0 = *(const half4v*)zrow;
    half4v b1 = *(const half4v*)(zrow + 4);

#pragma unroll 1
    for (int pt = 0; pt < CHUNK / 32; ++pt) {
        half8v Bf = __builtin_shufflevector(b0, b1, 0, 1, 2, 3, 4, 5, 6, 7);
        const float azc = az;

        const int nxt = (pt + 1) & (CHUNK / 32 - 1);
        const _Float16* bp = zrow + nxt * 32 * ZSTR;
        az = azqs[nxt * 32 + ln31];                  // ds_read_b32 (broadcast)
        b0 = *(const half4v*)bp;                     // ds_read_b64 x2
        b1 = *(const half4v*)(bp + 4);

        // Strip 0: MFMA then consume, before strip 1's MFMA -> only one
        // 16-reg dd tile transient at any time.
        float16v dd = __builtin_amdgcn_mfma_f32_32x32x16_f16(Af[0], Bf, biasC[0], 0, 0, 0);
#pragma unroll
        for (int r = 0; r < 16; ++r) {
            // fast 2^(dd+az'): v_fma_f32 + v_cvt_u32_f32 (neg->0) + v_add_f32
            float u = fmaf(dd[r], EXP2_SCALE, azc);
            acc[0][r] += __uint_as_float(__float2uint_rz(u));
        }

        dd = __builtin_amdgcn_mfma_f32_32x32x16_f16(Af[1], Bf, biasC[1], 0, 0, 0);
#pragma unroll
        for (int r = 0; r < 16; ++r) {
            float u = fmaf(dd[r], EXP2_SCALE, azc);
            acc[1][r] += __uint_as_float(__float2uint_rz(u));
        }
    }

    // ---- Epilogue: per-wave transpose-reduce through LDS, one pass per strip.
    __syncthreads();                        // all waves done reading zh
    float* scrw = scr + wave * SCR_WAVE;
#pragma unroll
    for (int s = 0; s < 2; ++s) {
#pragma unroll
        for (int r = 0; r < 16; ++r) {
            const int row = (r & 3) + 8 * (r >> 2) + 4 * hf;
            scrw[row * SCR_STRIDE + ln31] = acc[s][r];   // 2-way max bank alias = free
        }
        // Each lane sums half of row ln31 (16 f32), conflict-free banks (stride 33).
        const float* rp = scrw + ln31 * SCR_STRIDE + hf * 16;
        float sum = 0.f;
#pragma unroll
        for (int j = 0; j < 16; ++j) sum += rp[j];
        sum += __shfl_xor(sum, 32, 64);     // combine the two half-rows
        if (hf == 0)
            atomicAdd(&S[l * MM + m0 + s * 32 + ln31], sum); // 64 adds/address total
        // next pass reuses scrw: DS requests from one wave are processed in order,
        // so pass-2 writes cannot pass pass-1 reads.
    }
}

// Final: log, mean, constants. One workgroup of 1024 reading 16 KB.
__global__ void latent_reduce_kernel(const float* __restrict__ S,
                                     const float* __restrict__ log_sigma,
                                     float* __restrict__ out)
{
    const int t = threadIdx.x;
    float s = 0.f;
#pragma unroll
    for (int k = 0; k < 4; ++k) s += __logf(S[k * 1024 + t]);
#pragma unroll
    for (int off = 32; off > 0; off >>= 1) s += __shfl_down(s, off, 64);
    __shared__ float red[16];
    if ((t & 63) == 0) red[t >> 6] = s;
    __syncthreads();
    if (t == 0) {
        float tot = 0.f;
#pragma unroll
        for (int i = 0; i < 16; ++i) tot += red[i];
        const float ls = log_sigma[0];
        out[0] = -tot / (float)(NL * MM)
               + 32.0f * (2.0f * ls - 1.0f)   // 0.5*z_dim*(2ls-1), z_dim=64
               + 9.70406052783923f;           // ln(16384)
    }
}

extern "C" void kernel_launch(void* const* d_in, const int* in_sizes, int n_in,
                              void* d_out, int out_size, void* d_ws, size_t ws_size,
                              hipStream_t stream)
{
    const float* z  = (const float*)d_in[0];
    const float* e  = (const float*)d_in[1];
    const float* ls = (const float*)d_in[2];
    float* out = (float*)d_out;
    float* S   = (float*)d_ws;

    // ws is re-poisoned to 0xAA before every launch; zero the 16 KB accumulator.
    hipMemsetAsync(S, 0, NL * MM * sizeof(float), stream);
    latent_dist_kernel<<<NL * NMG * NCHUNK, 256, 0, stream>>>(z, e, ls, S);
    latent_reduce_kernel<<<1, 1024, 0, stream>>>(S, ls, out);
}